// Round 6
// baseline (606.774 us; speedup 1.0000x reference)
//
#include <hip/hip_runtime.h>
#include <hip/hip_bf16.h>
#include <stdint.h>

// Problem constants
#define N_ROWS 8192
#define IN_F   4096
#define OUT_F  4096
#define R_LORA 16
#define KP     4160   // padded K: 4096 data + col 4096 = bias-1.0 trick + zeros to /64

typedef __bf16 bf16_t;
typedef __attribute__((ext_vector_type(8))) __bf16 bf16x8;
typedef __attribute__((ext_vector_type(4))) float  f32x4;
typedef __attribute__((ext_vector_type(16))) float f32x16;

// ---------------------------------------------------------------------------
// async global->LDS, 16B per lane. LDS dest must be wave_base + lane*16.
// Per-lane SOURCE address is free-form (gather) — only the dest is constrained.
__device__ __forceinline__ void load16_lds(const bf16_t* g, bf16_t* l) {
    auto gp = (const __attribute__((address_space(1))) void*)g;
    auto lp = (__attribute__((address_space(3))) void*)(uint32_t)(uintptr_t)l;
    __builtin_amdgcn_global_load_lds(gp, lp, 16, 0, 0);
}

// ---------------------------------------------------------------------------
// prep, rewritten flat: one thread = one 16B output chunk. Perfectly
// coalesced stores; x/W loads are 32B/thread contiguous. Old block-based
// version ran ~240 us vs ~49 us streaming roofline. Same fp32 op order as
// before (W + sum_r (2*lB[r])*lA[r], r ascending) -> identical rounding.
#define CA   (N_ROWS * 512)              // A data chunks   (cols 0..4096)
#define CAP  (N_ROWS * 8)                // A pad chunks    (cols 4096..4160)
#define CB   (OUT_F * 512)               // B data chunks
#define CBP  (OUT_F * 8)                 // B pad chunks
#define PREP_CHUNKS (CA + CAP + CB + CBP)    // 6,389,760
#define PREP_BLOCKS (PREP_CHUNKS / 256)      // 24,960 (exact)

__global__ __launch_bounds__(256) void prep_flat(const float* __restrict__ x,
                                                 const float* __restrict__ W,
                                                 const float* __restrict__ bias,
                                                 const float* __restrict__ lA,
                                                 const float* __restrict__ lB,
                                                 bf16_t* __restrict__ Aw,
                                                 bf16_t* __restrict__ Bw) {
    int id = blockIdx.x * 256 + threadIdx.x;
    if (id < CA) {
        // Aw[row][c8*8 .. +8) = bf16(x[row][...])
        int row = id >> 9, c8 = id & 511;
        const float4* xp = (const float4*)(x + ((size_t)row << 12) + c8 * 8);
        float4 f0 = xp[0], f1 = xp[1];
        bf16x8 v;
        v[0] = (bf16_t)f0.x; v[1] = (bf16_t)f0.y;
        v[2] = (bf16_t)f0.z; v[3] = (bf16_t)f0.w;
        v[4] = (bf16_t)f1.x; v[5] = (bf16_t)f1.y;
        v[6] = (bf16_t)f1.z; v[7] = (bf16_t)f1.w;
        *(bf16x8*)(Aw + (size_t)row * KP + c8 * 8) = v;
    } else if (id < CA + CAP) {
        // Aw pad: col 4096 = 1.0, rest 0
        int p = id - CA, row = p >> 3, ch = p & 7;
        bf16x8 v;
#pragma unroll
        for (int i = 0; i < 8; ++i) v[i] = (bf16_t)0.0f;
        if (ch == 0) v[0] = (bf16_t)1.0f;
        *(bf16x8*)(Aw + (size_t)row * KP + IN_F + ch * 8) = v;
    } else if (id < CA + CAP + CB) {
        // Bw[o][c8*8..+8) = bf16(W + 2*lB.lA)
        int p = id - (CA + CAP), o = p >> 9, c8 = p & 511;
        const float4* lbp = (const float4*)(lB + o * R_LORA);
        float bl[R_LORA];
#pragma unroll
        for (int q = 0; q < 4; ++q) {
            float4 b4 = lbp[q];
            bl[q * 4 + 0] = 2.0f * b4.x; bl[q * 4 + 1] = 2.0f * b4.y;
            bl[q * 4 + 2] = 2.0f * b4.z; bl[q * 4 + 3] = 2.0f * b4.w;
        }
        const float4* wp = (const float4*)(W + ((size_t)o << 12) + c8 * 8);
        float4 w0 = wp[0], w1 = wp[1];
        float a[8] = {w0.x, w0.y, w0.z, w0.w, w1.x, w1.y, w1.z, w1.w};
#pragma unroll
        for (int r = 0; r < R_LORA; ++r) {
            const float4* ap = (const float4*)(lA + (size_t)r * IN_F + c8 * 8);
            float4 A0 = ap[0], A1 = ap[1];
            a[0] += bl[r] * A0.x; a[1] += bl[r] * A0.y;
            a[2] += bl[r] * A0.z; a[3] += bl[r] * A0.w;
            a[4] += bl[r] * A1.x; a[5] += bl[r] * A1.y;
            a[6] += bl[r] * A1.z; a[7] += bl[r] * A1.w;
        }
        bf16x8 v;
#pragma unroll
        for (int i = 0; i < 8; ++i) v[i] = (bf16_t)a[i];
        *(bf16x8*)(Bw + (size_t)o * KP + c8 * 8) = v;
    } else {
        // Bw pad: col 4096 = bias[o], rest 0
        int p = id - (CA + CAP + CB), o = p >> 3, ch = p & 7;
        bf16x8 v;
#pragma unroll
        for (int i = 0; i < 8; ++i) v[i] = (bf16_t)0.0f;
        if (ch == 0) v[0] = (bf16_t)bias[o];
        *(bf16x8*)(Bw + (size_t)o * KP + IN_F + ch * 8) = v;
    }
}

// ---------------------------------------------------------------------------
// NT bf16 GEMM: C[8192x4096] = Aw[8192xKP] * Bw[4096xKP]^T  (fp32 out)
//
// Staging/vmcnt = R2/R4 (proven): stage all 8 gloads at tile entry, counted
// vmcnt(8) -> the wait targets loads issued one full tile (~5400 cyc)
// earlier. ONLY change vs R4: the compute is split into 4 ks-phases with
// the m201 barrier discipline (T3):
//   {6 ds_read_b128 -> s_barrier -> lgkmcnt(0) -> sched_barrier(0)
//    -> setprio(1) -> 8 MFMA -> setprio(0) -> s_barrier}  x4
// Mechanism: R2/R4's coarse region dumps all 192 reads/CU into the LDS
// queue after the publish barrier; first MFMAs wait behind the ~2300-cyc
// drain -> MfmaUtil capped at 43%. With phases, the MFMA cluster of phase q
// EXECUTES (256 cyc/wave, post-issue) while phase q+1's reads drain: the
// wave issues 8 MFMAs, crosses the closing barrier, issues next reads, and
// only stalls on lgkmcnt — not on the MFMA pipe. lgkmcnt(0)+sched_barrier
// per rule #18 (hipcc hoists register-only MFMA past inline-asm waits).
// P3's closing barrier doubles as next tile's write-safety barrier.
// Read set identical to R4 (24 b128/wave/tile, no re-reads) -> numerics
// bit-identical.
#define BM 256
#define BN 256
#define BK 64
#define NT (KP / BK)    // 65

__global__ __launch_bounds__(512, 2) void gemm_bt(const bf16_t* __restrict__ A,
                                                  const bf16_t* __restrict__ B,
                                                  float* __restrict__ C) {
    __shared__ __align__(16) bf16_t lds[2][2][BM * BK];   // 128 KiB

    int bid = blockIdx.x;
    // XCD-aware bijective swizzle (512 blocks % 8 == 0)
    int swz = (bid & 7) * 64 + (bid >> 3);
    int bm  = swz & 31;              // 8192/256 = 32 row tiles
    int bn  = swz >> 5;              // 4096/256 = 16 col tiles
    int rowBase = bm * BM;
    int colBase = bn * BN;

    const int t    = threadIdx.x;
    const int lane = t & 63;
    const int wave = t >> 6;
    const int l31  = lane & 31;
    const int lhi  = lane >> 5;
    const int l7   = lane & 7;
    const int lsw  = l7 ^ (2 * (l31 >> 3));   // read-side swizzle constant
    const int wr   = wave >> 2;      // 0..1: rows [wr*128, +128)
    const int wc   = wave & 3;       // 0..3: cols [wc*64, +64)

    // per-fragment LDS element offsets (before the per-ks pos term)
    int rowOffA[4], colOffB[2];
#pragma unroll
    for (int rf = 0; rf < 4; ++rf) rowOffA[rf] = (wr * 128 + rf * 32 + l31) * BK;
#pragma unroll
    for (int cf = 0; cf < 2; ++cf) colOffB[cf] = (wc * 64 + cf * 32 + l31) * BK;

    // staging: chunk c = s*512 + t in [0,2048): r = c>>3 (256 rows), p = c&7.
    // LDS dest linear (required by global_load_lds); swizzle in SOURCE chunk:
    // slot p of row r receives global chunk  p ^ (r&7) ^ (2*((r>>3)&3)).
    uint32_t srcA[4], srcB[4];
#pragma unroll
    for (int s = 0; s < 4; ++s) {
        int c = s * 512 + t;
        int r = c >> 3, p = c & 7;
        int ck = p ^ (r & 7) ^ (2 * ((r >> 3) & 3));
        uint32_t off = (uint32_t)(r * KP + (ck << 3));
        srcA[s] = (uint32_t)(rowBase * KP) + off;
        srcB[s] = (uint32_t)(colBase * KP) + off;
    }

    auto stage = [&](int bsel, int k0) {   // 8 gload_lds per thread
#pragma unroll
        for (int s = 0; s < 4; ++s)
            load16_lds(A + srcA[s] + k0, &lds[bsel][0][(s * 512 + t) * 8]);
#pragma unroll
        for (int s = 0; s < 4; ++s)
            load16_lds(B + srcB[s] + k0, &lds[bsel][1][(s * 512 + t) * 8]);
    };

    f32x16 acc[4][2];
#pragma unroll
    for (int rf = 0; rf < 4; ++rf)
#pragma unroll
        for (int cf = 0; cf < 2; ++cf)
#pragma unroll
            for (int r = 0; r < 16; ++r) acc[rf][cf][r] = 0.f;

#define PHASE(ks)                                                              \
    do {                                                                       \
        const int pos = ((((ks) << 1) | lhi) ^ lsw) << 3;                      \
        bf16x8 af0 = *(const bf16x8*)&Ab[rowOffA[0] + pos];                    \
        bf16x8 af1 = *(const bf16x8*)&Ab[rowOffA[1] + pos];                    \
        bf16x8 af2 = *(const bf16x8*)&Ab[rowOffA[2] + pos];                    \
        bf16x8 af3 = *(const bf16x8*)&Ab[rowOffA[3] + pos];                    \
        bf16x8 bf0 = *(const bf16x8*)&Bb[colOffB[0] + pos];                    \
        bf16x8 bf1 = *(const bf16x8*)&Bb[colOffB[1] + pos];                    \
        __builtin_amdgcn_s_barrier();                                          \
        asm volatile("s_waitcnt lgkmcnt(0)" ::: "memory");                     \
        __builtin_amdgcn_sched_barrier(0);                                     \
        __builtin_amdgcn_s_setprio(1);                                         \
        acc[0][0] = __builtin_amdgcn_mfma_f32_32x32x16_bf16(af0, bf0, acc[0][0], 0, 0, 0); \
        acc[0][1] = __builtin_amdgcn_mfma_f32_32x32x16_bf16(af0, bf1, acc[0][1], 0, 0, 0); \
        acc[1][0] = __builtin_amdgcn_mfma_f32_32x32x16_bf16(af1, bf0, acc[1][0], 0, 0, 0); \
        acc[1][1] = __builtin_amdgcn_mfma_f32_32x32x16_bf16(af1, bf1, acc[1][1], 0, 0, 0); \
        acc[2][0] = __builtin_amdgcn_mfma_f32_32x32x16_bf16(af2, bf0, acc[2][0], 0, 0, 0); \
        acc[2][1] = __builtin_amdgcn_mfma_f32_32x32x16_bf16(af2, bf1, acc[2][1], 0, 0, 0); \
        acc[3][0] = __builtin_amdgcn_mfma_f32_32x32x16_bf16(af3, bf0, acc[3][0], 0, 0, 0); \
        acc[3][1] = __builtin_amdgcn_mfma_f32_32x32x16_bf16(af3, bf1, acc[3][1], 0, 0, 0); \
        __builtin_amdgcn_s_setprio(0);                                         \
        __builtin_amdgcn_s_barrier();                                          \
    } while (0)

    // prologue: tile 0 -> buf 0
    stage(0, 0);

    for (int kt = 0; kt < NT; ++kt) {
        const int cur = kt & 1;
        const int nb  = cur ^ 1;
        const bf16_t* Ab = &lds[cur][0][0];
        const bf16_t* Bb = &lds[cur][1][0];

        // buf[nb]'s last readers (tile kt-1) retired at kt-1's P3-close bar
        if (kt + 1 < NT) {
            stage(nb, (kt + 1) * BK);                        // 8 loads kt+1
            asm volatile("s_waitcnt vmcnt(8)" ::: "memory"); // kt landed
        } else {
            asm volatile("s_waitcnt vmcnt(0)" ::: "memory"); // tail drain
        }
        __builtin_amdgcn_s_barrier();                        // publish kt

        PHASE(0);
        PHASE(1);
        PHASE(2);
        PHASE(3);   // closing barrier = write-safety for next tile's stage
    }
#undef PHASE

    // epilogue: C/D layout col=l&31, row=(reg&3)+8*(reg>>2)+4*(l>>5)
#pragma unroll
    for (int rf = 0; rf < 4; ++rf) {
        int rB = rowBase + wr * 128 + rf * 32 + 4 * lhi;
#pragma unroll
        for (int cf = 0; cf < 2; ++cf) {
            int col = colBase + wc * 64 + cf * 32 + l31;
#pragma unroll
            for (int reg = 0; reg < 16; ++reg) {
                int row = rB + (reg & 3) + 8 * (reg >> 2);
                C[(size_t)row * OUT_F + col] = acc[rf][cf][reg];
            }
        }
    }
}

// ---------------------------------------------------------------------------
extern "C" void kernel_launch(void* const* d_in, const int* in_sizes, int n_in,
                              void* d_out, int out_size, void* d_ws, size_t ws_size,
                              hipStream_t stream) {
    const float* x  = (const float*)d_in[0];   // (8192, 4096)
    const float* W  = (const float*)d_in[1];   // (4096, 4096)
    const float* b  = (const float*)d_in[2];   // (4096,)
    const float* lA = (const float*)d_in[3];   // (16, 4096)
    const float* lB = (const float*)d_in[4];   // (4096, 16)
    float* out = (float*)d_out;                // (8192, 4096) fp32

    // workspace layout: Aw (8192 x 4160 bf16), Bw (4096 x 4160 bf16) ~102.3 MB
    bf16_t* Aw = (bf16_t*)d_ws;
    bf16_t* Bw = Aw + (size_t)N_ROWS * KP;

    prep_flat<<<PREP_BLOCKS, 256, 0, stream>>>(x, W, b, lA, lB, Aw, Bw);
    gemm_bt<<<(N_ROWS / BM) * (OUT_F / BN), 512, 0, stream>>>(Aw, Bw, out);
}

// Round 7
// 549.771 us; speedup vs baseline: 1.1037x; 1.1037x over previous
//
#include <hip/hip_runtime.h>
#include <hip/hip_bf16.h>
#include <stdint.h>

// Problem constants
#define N_ROWS 8192
#define IN_F   4096
#define OUT_F  4096
#define R_LORA 16
#define KP     4160   // padded K: 4096 data + col 4096 = bias-1.0 trick + zeros to /64

typedef __bf16 bf16_t;
typedef __attribute__((ext_vector_type(8))) __bf16 bf16x8;
typedef __attribute__((ext_vector_type(4))) __bf16 bf16x4;
typedef __attribute__((ext_vector_type(4))) float  f32x4;
typedef __attribute__((ext_vector_type(16))) float f32x16;

// ---------------------------------------------------------------------------
// async global->LDS, 16B per lane. LDS dest must be wave_base + lane*16.
// Per-lane SOURCE address is free-form (gather) — only the dest is constrained.
__device__ __forceinline__ void load16_lds(const bf16_t* g, bf16_t* l) {
    auto gp = (const __attribute__((address_space(1))) void*)g;
    auto lp = (__attribute__((address_space(3))) void*)(uint32_t)(uintptr_t)l;
    __builtin_amdgcn_global_load_lds(gp, lp, 16, 0, 0);
}

// ---------------------------------------------------------------------------
// prep (REVERTED to the R4 version): timing decomposition across R0-R6 shows
// dur_us = ~215us fixed harness overhead + gemm + prep, with this version at
// ~27us (near its 47us... actually below-roofline-estimate; the flat rewrite
// with 2.3x the VMEM instructions measured ~58us). Keep this one.
#define PREPA_BLOCKS 2048

__global__ __launch_bounds__(256) void prep_fused(const float* __restrict__ x,
                                                  const float* __restrict__ W,
                                                  const float* __restrict__ bias,
                                                  const float* __restrict__ lA,
                                                  const float* __restrict__ lB,
                                                  bf16_t* __restrict__ Aw,
                                                  bf16_t* __restrict__ Bw) {
    int b = blockIdx.x;
    int t = threadIdx.x;
    if (b < PREPA_BLOCKS) {
        int row0 = b * 4;
        for (int rr = 0; rr < 4; ++rr) {
            int row = row0 + rr;
            const float4* xr = (const float4*)(x + (size_t)row * IN_F);
            bf16_t* ar = Aw + (size_t)row * KP;
            for (int s = t; s < 512; s += 256) {
                float4 f0 = xr[2 * s];
                float4 f1 = xr[2 * s + 1];
                bf16x8 v;
                v[0] = (bf16_t)f0.x; v[1] = (bf16_t)f0.y;
                v[2] = (bf16_t)f0.z; v[3] = (bf16_t)f0.w;
                v[4] = (bf16_t)f1.x; v[5] = (bf16_t)f1.y;
                v[6] = (bf16_t)f1.z; v[7] = (bf16_t)f1.w;
                *(bf16x8*)(ar + s * 8) = v;
            }
            if (t < 64) ar[IN_F + t] = (t == 0) ? (bf16_t)1.0f : (bf16_t)0.0f;
        }
    } else {
        int o0 = (b - PREPA_BLOCKS) * 4;
        float bl[4][R_LORA];
        for (int oo = 0; oo < 4; ++oo)
            for (int r = 0; r < R_LORA; ++r)
                bl[oo][r] = 2.0f * lB[(o0 + oo) * R_LORA + r];

        for (int j = 0; j < IN_F / (256 * 4); ++j) {   // 4 iterations
            int i4 = (j * 256 + t) * 4;
            f32x4 acc[4];
            for (int oo = 0; oo < 4; ++oo) {
                float4 w = *(const float4*)(W + (size_t)(o0 + oo) * IN_F + i4);
                acc[oo] = (f32x4){w.x, w.y, w.z, w.w};
            }
            for (int r = 0; r < R_LORA; ++r) {
                float4 a = *(const float4*)(lA + (size_t)r * IN_F + i4);
                for (int oo = 0; oo < 4; ++oo) {
                    acc[oo][0] += bl[oo][r] * a.x;
                    acc[oo][1] += bl[oo][r] * a.y;
                    acc[oo][2] += bl[oo][r] * a.z;
                    acc[oo][3] += bl[oo][r] * a.w;
                }
            }
            for (int oo = 0; oo < 4; ++oo) {
                bf16x4 v;
                v[0] = (bf16_t)acc[oo][0]; v[1] = (bf16_t)acc[oo][1];
                v[2] = (bf16_t)acc[oo][2]; v[3] = (bf16_t)acc[oo][3];
                *(bf16x4*)(Bw + (size_t)(o0 + oo) * KP + i4) = v;
            }
        }
        {   // pad columns: 4 rows x 64 cols = 256 slots, one per thread
            int oo = t >> 6;
            int c  = IN_F + (t & 63);
            float v = (c == IN_F) ? bias[o0 + oo] : 0.0f;
            Bw[(size_t)(o0 + oo) * KP + c] = (bf16_t)v;
        }
    }
}

// ---------------------------------------------------------------------------
// NT bf16 GEMM: C[8192x4096] = Aw[8192xKP] * Bw[4096xKP]^T  (fp32 out)
//
// Faithful m201 quadrant-phase schedule. THE mechanism my R3/R6 ports
// missed: each phase computes one C-QUADRANT -> its 8 MFMAs write a
// DISTINCT acc set -> no register dependence on the previous phase's
// still-executing MFMAs -> the wave issues MFMAs, crosses the closing
// barrier, and issues next-phase ds_reads while the matrix pipe drains.
// (R6's ks-phases chained the same acc -> serialized; R3 lacked the
// read/barrier/lgkmcnt discipline.)
//
// Per K-tile kt (buf cur=kt&1; stage tile kt+1 -> buf nb, one A/B half-pair
// of 2 gloads per phase). Quadrant order (0,0),(1,0),(1,1),(0,1) carries one
// operand across each phase boundary (only changed operand re-read; A0 read
// twice -> 32 b128/wave/tile). Phase body:
//   [ds_reads] [stage 2 gloads] [sched_barrier] s_barrier
//   lgkmcnt(0) sched_barrier setprio(1) 8x MFMA setprio(0)
//   [counted vmcnt] s_barrier
// Derived waits (queue-traced; loads issued >=3 phases before their wait):
//   end ph0: vmcnt(4)  queue [A1,B1](kt)+A0'(kt+1)=6 -> retires A1(kt)
//   end ph1: vmcnt(4)  queue [B1,A0',B0']=6          -> retires B1(kt)
//   end ph2: none
//   end ph3: vmcnt(4)  queue [A0',B0',A1',B1']=8     -> retires A0',B0'
// Tail tile: no stages; waits become vmcnt(2)/vmcnt(0)/none.
// Race audit: stage into buf nb at kt-ph_p; prior readers (tile kt-1) all
// retired their ds_reads before kt-1's ph3 closing barrier, which precedes
// every kt stage in program order for every wave.
#define BM 256
#define BN 256
#define BK 64
#define NT (KP / BK)    // 65

__global__ __launch_bounds__(512, 2) void gemm_bt(const bf16_t* __restrict__ A,
                                                  const bf16_t* __restrict__ B,
                                                  float* __restrict__ C) {
    __shared__ __align__(16) bf16_t lds[2][2][BM * BK];   // 128 KiB

    int bid = blockIdx.x;
    // XCD-aware bijective swizzle (512 blocks % 8 == 0)
    int swz = (bid & 7) * 64 + (bid >> 3);
    int bm  = swz & 31;              // 8192/256 = 32 row tiles
    int bn  = swz >> 5;              // 4096/256 = 16 col tiles
    int rowBase = bm * BM;
    int colBase = bn * BN;

    const int t    = threadIdx.x;
    const int lane = t & 63;
    const int wave = t >> 6;
    const int l31  = lane & 31;
    const int lhi  = lane >> 5;
    const int l7   = lane & 7;
    const int lsw  = l7 ^ (2 * (l31 >> 3));   // read-side swizzle constant
    const int wr   = wave >> 2;      // 0..1: 64-row slice within a 128-row half
    const int wc   = wave & 3;       // 0..3: 32-col slice within a 128-col half

    // LDS element offsets: A rows per [qa][i], B cols per [qb]
    int rowA_[2][2], colB_[2];
#pragma unroll
    for (int qa = 0; qa < 2; ++qa)
#pragma unroll
        for (int i = 0; i < 2; ++i)
            rowA_[qa][i] = (qa * 128 + wr * 64 + i * 32 + l31) * BK;
#pragma unroll
    for (int qb = 0; qb < 2; ++qb)
        colB_[qb] = (qb * 128 + wc * 32 + l31) * BK;
    int pos_[4];
#pragma unroll
    for (int ks = 0; ks < 4; ++ks) pos_[ks] = ((((ks << 1) | lhi)) ^ lsw) << 3;

    // staging: chunk c = s*512 + t in [0,2048): r = c>>3 (256 rows), p = c&7.
    // LDS dest linear (required by global_load_lds); swizzle in SOURCE chunk.
    // Pair s={0,1} covers rows [0,128) = half 0; s={2,3} rows [128,256) = half 1.
    uint32_t srcA[4], srcB[4];
#pragma unroll
    for (int s = 0; s < 4; ++s) {
        int c = s * 512 + t;
        int r = c >> 3, p = c & 7;
        int ck = p ^ (r & 7) ^ (2 * ((r >> 3) & 3));
        uint32_t off = (uint32_t)(r * KP + (ck << 3));
        srcA[s] = (uint32_t)(rowBase * KP) + off;
        srcB[s] = (uint32_t)(colBase * KP) + off;
    }

    auto stage2A = [&](int bsel, int k0, int half) {
#pragma unroll
        for (int s2 = 0; s2 < 2; ++s2) {
            int s = half * 2 + s2;
            load16_lds(A + srcA[s] + k0, &lds[bsel][0][(s * 512 + t) * 8]);
        }
    };
    auto stage2B = [&](int bsel, int k0, int half) {
#pragma unroll
        for (int s2 = 0; s2 < 2; ++s2) {
            int s = half * 2 + s2;
            load16_lds(B + srcB[s] + k0, &lds[bsel][1][(s * 512 + t) * 8]);
        }
    };

    f32x16 acc[4][2];
#pragma unroll
    for (int q = 0; q < 4; ++q)
#pragma unroll
        for (int i = 0; i < 2; ++i)
#pragma unroll
            for (int r = 0; r < 16; ++r) acc[q][i][r] = 0.f;

    bf16x8 af[2][4];   // current A-half fragments: [i][ks]
    bf16x8 bfr[4];     // current B-half fragments: [ks]

#define RD_A(qa_)                                                              \
    do {                                                                       \
        _Pragma("unroll")                                                      \
        for (int i = 0; i < 2; ++i)                                            \
            _Pragma("unroll")                                                  \
            for (int ks = 0; ks < 4; ++ks)                                     \
                af[i][ks] = *(const bf16x8*)&Ab[rowA_[qa_][i] + pos_[ks]];     \
    } while (0)

#define RD_B(qb_)                                                              \
    do {                                                                       \
        _Pragma("unroll")                                                      \
        for (int ks = 0; ks < 4; ++ks)                                         \
            bfr[ks] = *(const bf16x8*)&Bb[colB_[qb_] + pos_[ks]];              \
    } while (0)

#define MMA_Q(q_)                                                              \
    do {                                                                       \
        asm volatile("s_waitcnt lgkmcnt(0)" ::: "memory");                     \
        __builtin_amdgcn_sched_barrier(0);                                     \
        __builtin_amdgcn_s_setprio(1);                                         \
        _Pragma("unroll")                                                      \
        for (int ks = 0; ks < 4; ++ks)                                         \
            _Pragma("unroll")                                                  \
            for (int i = 0; i < 2; ++i)                                        \
                acc[q_][i] = __builtin_amdgcn_mfma_f32_32x32x16_bf16(          \
                    af[i][ks], bfr[ks], acc[q_][i], 0, 0, 0);                  \
        __builtin_amdgcn_s_setprio(0);                                         \
    } while (0)

#define SBAR __builtin_amdgcn_s_barrier()
#define PIN  __builtin_amdgcn_sched_barrier(0)

    // prologue: all 4 half-pairs of tile 0 -> buf 0, then publish (like a
    // steady-state end-of-ph3: queue 8 -> vmcnt(4) retires A0,B0 of tile 0)
    stage2A(0, 0, 0);
    stage2B(0, 0, 0);
    stage2A(0, 0, 1);
    stage2B(0, 0, 1);
    asm volatile("s_waitcnt vmcnt(4)" ::: "memory");
    SBAR;

    for (int kt = 0; kt < NT - 1; ++kt) {
        const int cur = kt & 1;
        const int nb  = cur ^ 1;
        const int k1  = (kt + 1) * BK;
        const bf16_t* Ab = &lds[cur][0][0];
        const bf16_t* Bb = &lds[cur][1][0];

        // ph0: quadrant (0,0) — read A0+B0 (12), stage A0'(kt+1)
        RD_A(0); RD_B(0);
        stage2A(nb, k1, 0);
        asm volatile("s_waitcnt lgkmcnt(8)" ::: "memory");
        PIN; SBAR;
        MMA_Q(0);
        asm volatile("s_waitcnt vmcnt(4)" ::: "memory");   // A1(kt) landed
        SBAR;
        // ph1: quadrant (1,0) — read A1 (8), reuse B0; stage B0'
        RD_A(1);
        stage2B(nb, k1, 0);
        PIN; SBAR;
        MMA_Q(1);
        asm volatile("s_waitcnt vmcnt(4)" ::: "memory");   // B1(kt) landed
        SBAR;
        // ph2: quadrant (1,1) — read B1 (4), reuse A1; stage A1'
        RD_B(1);
        stage2A(nb, k1, 1);
        PIN; SBAR;
        MMA_Q(2);
        SBAR;
        // ph3: quadrant (0,1) — re-read A0 (8), reuse B1; stage B1'
        RD_A(0);
        stage2B(nb, k1, 1);
        PIN; SBAR;
        MMA_Q(3);
        asm volatile("s_waitcnt vmcnt(4)" ::: "memory");   // A0',B0' landed
        SBAR;
    }
    {   // tail tile kt = NT-1 (buf 0): no staging; drain waits 2/0/none
        const bf16_t* Ab = &lds[0][0][0];
        const bf16_t* Bb = &lds[0][1][0];
        RD_A(0); RD_B(0);
        asm volatile("s_waitcnt lgkmcnt(8)" ::: "memory");
        PIN; SBAR;
        MMA_Q(0);
        asm volatile("s_waitcnt vmcnt(2)" ::: "memory");   // A1 landed
        SBAR;
        RD_A(1);
        PIN; SBAR;
        MMA_Q(1);
        asm volatile("s_waitcnt vmcnt(0)" ::: "memory");   // B1 landed
        SBAR;
        RD_B(1);
        PIN; SBAR;
        MMA_Q(2);
        SBAR;
        RD_A(0);
        PIN; SBAR;
        MMA_Q(3);
    }
#undef RD_A
#undef RD_B
#undef MMA_Q
#undef SBAR
#undef PIN

    // epilogue: C/D layout col=l&31, row=(reg&3)+8*(reg>>2)+4*(l>>5)
    const int qa_[4] = {0, 1, 1, 0};
    const int qb_[4] = {0, 0, 1, 1};
#pragma unroll
    for (int q = 0; q < 4; ++q) {
#pragma unroll
        for (int i = 0; i < 2; ++i) {
            int rB  = rowBase + qa_[q] * 128 + wr * 64 + i * 32 + 4 * lhi;
            int col = colBase + qb_[q] * 128 + wc * 32 + l31;
#pragma unroll
            for (int reg = 0; reg < 16; ++reg) {
                int row = rB + (reg & 3) + 8 * (reg >> 2);
                C[(size_t)row * OUT_F + col] = acc[q][i][reg];
            }
        }
    }
}

// ---------------------------------------------------------------------------
extern "C" void kernel_launch(void* const* d_in, const int* in_sizes, int n_in,
                              void* d_out, int out_size, void* d_ws, size_t ws_size,
                              hipStream_t stream) {
    const float* x  = (const float*)d_in[0];   // (8192, 4096)
    const float* W  = (const float*)d_in[1];   // (4096, 4096)
    const float* b  = (const float*)d_in[2];   // (4096,)
    const float* lA = (const float*)d_in[3];   // (16, 4096)
    const float* lB = (const float*)d_in[4];   // (4096, 16)
    float* out = (float*)d_out;                // (8192, 4096) fp32

    // workspace layout: Aw (8192 x 4160 bf16), Bw (4096 x 4160 bf16) ~102.3 MB
    bf16_t* Aw = (bf16_t*)d_ws;
    bf16_t* Bw = Aw + (size_t)N_ROWS * KP;

    prep_fused<<<PREPA_BLOCKS + OUT_F / 4, 256, 0, stream>>>(x, W, b, lA, lB, Aw, Bw);
    gemm_bt<<<(N_ROWS / BM) * (OUT_F / BN), 512, 0, stream>>>(Aw, Bw, out);
}